// Round 4
// baseline (323.833 us; speedup 1.0000x reference)
//
#include <hip/hip_runtime.h>
#include <math.h>

#define HH 64
#define WW 64
#define KS 5
#define CPP 8
#define NPOS 48
#define CHAN (NPOS * CPP)   // 384
#define NBATCH 32

// DPP wave shifts: full-rate VALU cross-lane, no LDS pipe, no lgkmcnt.
// wave_shr:1 (0x138): lane i <- lane i-1.  wave_shl:1 (0x130): lane i <- lane i+1.
// bound_ctrl=true: out-of-wave lanes read 0 (matches conv zero-pad at x edges,
// and wxm masks make the value irrelevant anyway).
__device__ __forceinline__ float dpp_shr1(float v) {
    return __int_as_float(__builtin_amdgcn_mov_dpp(__float_as_int(v), 0x138, 0xF, 0xF, true));
}
__device__ __forceinline__ float dpp_shl1(float v) {
    return __int_as_float(__builtin_amdgcn_mov_dpp(__float_as_int(v), 0x130, 0xF, 0xF, true));
}

// One wave per TWO planes (same position group => shared offset/weights and
// identical per-lane addresses; only the scalar base differs). Lane = x column.
// Per displaced row: 2 coalesced global_load_dword (one per plane), horizontal
// 5-tap via chained DPP wave shifts + masked weights, vertical 5-tap via
// 5-register sliding windows. 6144 waves = 24 waves/CU -> single occupancy
// round; two independent chains per wave double MLP.
__global__ __launch_bounds__(256)
void displace_dpp2_kernel(const float* __restrict__ x,
                          const float* __restrict__ off,
                          float* __restrict__ out)
{
    const int t    = threadIdx.x;
    const int lane = t & 63;
    const int pair = __builtin_amdgcn_readfirstlane(blockIdx.x * 4 + (t >> 6));
    const int plane0 = pair * 2;                 // even channel of a cpp-group
    const int p = (plane0 % CHAN) / CPP;         // wave-uniform position index

    const float* __restrict__ src0 = x   + (size_t)plane0 * (HH * WW);
    const float* __restrict__ src1 = src0 + (HH * WW);
    float*       __restrict__ dst0 = out + (size_t)plane0 * (HH * WW);
    float*       __restrict__ dst1 = dst0 + (HH * WW);

    // --- offset -> integer shift + separable Gaussian weights (sigma=0.5) ---
    const float offx = off[2 * p + 0];
    const float offy = off[2 * p + 1];
    const float rxf = rintf(offx), ryf = rintf(offy);
    const int   dx = (int)rxf,     dy = (int)ryf;
    const float subx = offx - rxf, suby = offy - ryf;

    float wxr[KS], wy[KS];
    float sumx = 0.f, sumy = 0.f;
    #pragma unroll
    for (int k = 0; k < KS; ++k) {
        const float ax = (float)(k - 2) + subx;
        const float ay = (float)(k - 2) + suby;
        wxr[k] = __expf(-2.0f * ax * ax);
        wy[k]  = __expf(-2.0f * ay * ay);
        sumx += wxr[k];
        sumy += wy[k];
    }
    const float inv = 1.0f / (sumx * sumy);

    // tap k reads displaced column lane+k-2: weight 0 if outside [0,W) (conv
    // zero-pad). Full 2D normalization folded in.
    float wxm[KS];
    #pragma unroll
    for (int k = 0; k < KS; ++k) {
        const int sl = lane + (k - 2);
        wxm[k] = ((unsigned)sl < (unsigned)WW) ? wxr[k] * inv : 0.0f;
    }

    // per-lane source column for displaced value D[lane] = src[.][lane-dx]
    const int   sx  = lane - dx;
    const float mx  = ((unsigned)sx < (unsigned)WW) ? 1.0f : 0.0f;
    const int   sxc = min(max(sx, 0), WW - 1);

    float hb0[5], hb1[5];   // sliding windows of horizontally-filtered rows

    #pragma unroll
    for (int i = 0; i < HH + 4; ++i) {
        const int  yy = i - 2;            // displaced row
        const int  sy = yy - dy;          // source row (wave-uniform)
        const bool rowok = (((unsigned)yy < (unsigned)HH) & ((unsigned)sy < (unsigned)HH));
        const int  syc = min(max(sy, 0), HH - 1);
        const int  ofs = syc * WW + sxc;

        const float v0 = src0[ofs] * mx;
        const float v1 = src1[ofs] * mx;

        const float a_m1 = dpp_shr1(v0);
        const float b_m1 = dpp_shr1(v1);
        const float a_m2 = dpp_shr1(a_m1);
        const float b_m2 = dpp_shr1(b_m1);
        const float a_p1 = dpp_shl1(v0);
        const float b_p1 = dpp_shl1(v1);
        const float a_p2 = dpp_shl1(a_p1);
        const float b_p2 = dpp_shl1(b_p1);

        float h0 = wxm[0] * a_m2;
        float h1 = wxm[0] * b_m2;
        h0 = fmaf(wxm[1], a_m1, h0);
        h1 = fmaf(wxm[1], b_m1, h1);
        h0 = fmaf(wxm[2], v0,   h0);
        h1 = fmaf(wxm[2], v1,   h1);
        h0 = fmaf(wxm[3], a_p1, h0);
        h1 = fmaf(wxm[3], b_p1, h1);
        h0 = fmaf(wxm[4], a_p2, h0);
        h1 = fmaf(wxm[4], b_p2, h1);
        hb0[i % 5] = rowok ? h0 : 0.0f;
        hb1[i % 5] = rowok ? h1 : 0.0f;

        if (i >= 4) {
            const int y = i - 4;
            float c0 = wy[0] * hb0[(i - 4) % 5];
            float c1 = wy[0] * hb1[(i - 4) % 5];
            c0 = fmaf(wy[1], hb0[(i - 3) % 5], c0);
            c1 = fmaf(wy[1], hb1[(i - 3) % 5], c1);
            c0 = fmaf(wy[2], hb0[(i - 2) % 5], c0);
            c1 = fmaf(wy[2], hb1[(i - 2) % 5], c1);
            c0 = fmaf(wy[3], hb0[(i - 1) % 5], c0);
            c1 = fmaf(wy[3], hb1[(i - 1) % 5], c1);
            c0 = fmaf(wy[4], hb0[(i - 0) % 5], c0);
            c1 = fmaf(wy[4], hb1[(i - 0) % 5], c1);
            dst0[y * WW + lane] = c0;
            dst1[y * WW + lane] = c1;
        }
    }
}

extern "C" void kernel_launch(void* const* d_in, const int* in_sizes, int n_in,
                              void* d_out, int out_size, void* d_ws, size_t ws_size,
                              hipStream_t stream) {
    const float* x   = (const float*)d_in[0];
    const float* off = (const float*)d_in[1];
    float* out = (float*)d_out;

    // 12288 planes / 2 per wave = 6144 waves; 4 waves per 256-thread block
    const int blocks = NBATCH * CHAN / 2 / 4;   // 1536 -> 6 blocks/CU, 24 waves/CU
    displace_dpp2_kernel<<<blocks, 256, 0, stream>>>(x, off, out);
}